// Round 1
// baseline (13144.113 us; speedup 1.0000x reference)
//
#include <hip/hip_runtime.h>
#include <cstdint>
#include <cstddef>

#define B_  8
#define S_  2048
#define DM  1024
#define FF  4096
#define NE  16
#define CAP 256
#define TOK (B_ * S_)

#define MT 32    // rows per FFN block
#define FT 128   // FF chunk

// ---------------- K1: router (one wave per token) ----------------
__global__ __launch_bounds__(256) void router_k(
    const float* __restrict__ hidden, const float* __restrict__ rw,
    float* __restrict__ logits_out, float* __restrict__ eidx_f,
    int* __restrict__ eidx, float* __restrict__ mp)
{
  int wid  = (blockIdx.x * blockDim.x + threadIdx.x) >> 6;  // token
  int lane = threadIdx.x & 63;
  if (wid >= TOK) return;
  const float* h = hidden + (size_t)wid * DM;

  float acc[NE];
#pragma unroll
  for (int e = 0; e < NE; ++e) acc[e] = 0.f;

#pragma unroll
  for (int t = 0; t < 4; ++t) {
    int k0 = t * 256 + lane * 4;
    float4 hv = *reinterpret_cast<const float4*>(h + k0);
    float hx[4] = {hv.x, hv.y, hv.z, hv.w};
#pragma unroll
    for (int j = 0; j < 4; ++j) {
      const float4* r4 = reinterpret_cast<const float4*>(rw + (size_t)(k0 + j) * NE);
      float4 r0 = r4[0], r1 = r4[1], r2 = r4[2], r3 = r4[3];
      acc[0]  += hx[j] * r0.x;  acc[1]  += hx[j] * r0.y;
      acc[2]  += hx[j] * r0.z;  acc[3]  += hx[j] * r0.w;
      acc[4]  += hx[j] * r1.x;  acc[5]  += hx[j] * r1.y;
      acc[6]  += hx[j] * r1.z;  acc[7]  += hx[j] * r1.w;
      acc[8]  += hx[j] * r2.x;  acc[9]  += hx[j] * r2.y;
      acc[10] += hx[j] * r2.z;  acc[11] += hx[j] * r2.w;
      acc[12] += hx[j] * r3.x;  acc[13] += hx[j] * r3.y;
      acc[14] += hx[j] * r3.z;  acc[15] += hx[j] * r3.w;
    }
  }
  // butterfly reduce -> every lane holds all 16 logits
#pragma unroll
  for (int e = 0; e < NE; ++e) {
    float v = acc[e];
#pragma unroll
    for (int off = 32; off > 0; off >>= 1) v += __shfl_xor(v, off, 64);
    acc[e] = v;
  }
  if (lane < NE) logits_out[(size_t)wid * NE + lane] = acc[lane];
  if (lane == 0) {
    float m = acc[0]; int am = 0;
#pragma unroll
    for (int e = 1; e < NE; ++e) { if (acc[e] > m) { m = acc[e]; am = e; } }
    float s = 0.f;
#pragma unroll
    for (int e = 0; e < NE; ++e) s += expf(acc[e] - m);
    mp[wid]     = 1.f / s;          // max prob = exp(m-m)/sum
    eidx[wid]   = am;
    eidx_f[wid] = (float)am;        // expert_index output region (as float)
  }
}

// ---------------- K2: per-batch capacity scan (1 wave per batch) ----------------
__global__ __launch_bounds__(64) void scan_k(
    const int* __restrict__ eidx, int* __restrict__ slots, int* __restrict__ counts)
{
  int b = blockIdx.x;
  int lane = threadIdx.x;
  int cnt[NE];
#pragma unroll
  for (int e = 0; e < NE; ++e) cnt[e] = 0;
  unsigned long long below = (lane == 0) ? 0ull : ((~0ull) >> (64 - lane));

  for (int s0 = 0; s0 < S_; s0 += 64) {
    int e = eidx[b * S_ + s0 + lane];
    int pos = 0;
#pragma unroll
    for (int j = 0; j < NE; ++j) {
      unsigned long long mball = __ballot(e == j);
      if (e == j) pos = cnt[j] + __popcll(mball & below);
      cnt[j] += __popcll(mball);
    }
    if (pos < CAP) slots[((size_t)b * NE + e) * CAP + pos] = s0 + lane;
  }
  if (lane == 0) {
#pragma unroll
    for (int e = 0; e < NE; ++e) counts[b * NE + e] = min(cnt[e], CAP);
  }
}

// ---------------- K3: passthrough combine: out = mp * hidden (all tokens) ----------------
__global__ __launch_bounds__(256) void passthrough_k(
    const float* __restrict__ hidden, const float* __restrict__ mp, float* __restrict__ out)
{
  size_t i = (size_t)blockIdx.x * blockDim.x + threadIdx.x;  // float4 index
  float4 v = reinterpret_cast<const float4*>(hidden)[i];
  float m = mp[i >> 8];  // DM/4 = 256 float4 per token
  float4 r; r.x = v.x * m; r.y = v.y * m; r.z = v.z * m; r.w = v.w * m;
  reinterpret_cast<float4*>(out)[i] = r;
}

// ---------------- K4: fused per-expert FFN, fp32 vector ----------------
__global__ __launch_bounds__(512) void moe_ffn_k(
    const float* __restrict__ hidden,
    const float* __restrict__ wi, const float* __restrict__ wo,
    const int* __restrict__ slots, const int* __restrict__ counts,
    const float* __restrict__ mp, float* __restrict__ out)
{
  const int e = blockIdx.y;
  const int tile = blockIdx.x;

  int cnt[B_], off[B_];
  int Re = 0;
#pragma unroll
  for (int b = 0; b < B_; ++b) { cnt[b] = counts[b * NE + e]; off[b] = Re; Re += cnt[b]; }
  const int r0 = tile * MT;
  if (r0 >= Re) return;

  __shared__ int   s_tok[MT];
  __shared__ float s_mp[MT];
  __shared__ int   s_val[MT];
  __shared__ float h_lds[MT][FT];

  const int t = threadIdx.x;
  if (t < MT) {
    int r = r0 + t;
    int tok = 0, val = 0; float m = 0.f;
    if (r < Re) {
      int b = 0;
      while (b < B_ - 1 && r >= off[b] + cnt[b]) ++b;
      int c = r - off[b];
      int s = slots[((size_t)b * NE + e) * CAP + c];
      tok = b * S_ + s; val = 1; m = mp[tok];
    }
    s_tok[t] = tok; s_mp[t] = m; s_val[t] = val;
  }
  __syncthreads();

  const int tx = t & 63;
  const int ty = t >> 6;  // 8 waves; each wave owns rows ty*4 .. ty*4+3
  const float* wi_e = wi + (size_t)e * DM * FF;
  const float* wo_e = wo + (size_t)e * FF * DM;

  const float* xp[4];
#pragma unroll
  for (int j = 0; j < 4; ++j) xp[j] = hidden + (size_t)s_tok[ty * 4 + j] * DM;

  float acc[4][16];
#pragma unroll
  for (int j = 0; j < 4; ++j)
#pragma unroll
    for (int i = 0; i < 16; ++i) acc[j][i] = 0.f;

  for (int fc = 0; fc < FF; fc += FT) {
    // ---- GEMM1: h[32][FT] = relu(x @ wi[:, fc:fc+FT]); cols f = fc + tx + {0,64}
    float a1[4][2];
#pragma unroll
    for (int j = 0; j < 4; ++j) { a1[j][0] = 0.f; a1[j][1] = 0.f; }
    const float* wic = wi_e + (size_t)fc + tx;
    for (int k = 0; k < DM; k += 4) {
      float xs[4][4];
#pragma unroll
      for (int j = 0; j < 4; ++j) {
        float4 xv = *reinterpret_cast<const float4*>(xp[j] + k);
        xs[j][0] = xv.x; xs[j][1] = xv.y; xs[j][2] = xv.z; xs[j][3] = xv.w;
      }
      const float* wk = wic + (size_t)k * FF;
#pragma unroll
      for (int q = 0; q < 4; ++q) {
        float wa = wk[(size_t)q * FF];
        float wb = wk[(size_t)q * FF + 64];
#pragma unroll
        for (int j = 0; j < 4; ++j) {
          a1[j][0] += xs[j][q] * wa;
          a1[j][1] += xs[j][q] * wb;
        }
      }
    }
#pragma unroll
    for (int j = 0; j < 4; ++j) {
      h_lds[ty * 4 + j][tx]      = fmaxf(a1[j][0], 0.f);
      h_lds[ty * 4 + j][tx + 64] = fmaxf(a1[j][1], 0.f);
    }
    __syncthreads();

    // ---- GEMM2: acc += h @ wo[fc:fc+FT, :]; cols d = g*256 + tx*4 + i
    const float* worow = wo_e + (size_t)fc * DM;
#pragma unroll 2
    for (int f = 0; f < FT; ++f) {
      float hv[4];
#pragma unroll
      for (int j = 0; j < 4; ++j) hv[j] = h_lds[ty * 4 + j][f];
      const float* wr = worow + (size_t)f * DM + tx * 4;
#pragma unroll
      for (int g = 0; g < 4; ++g) {
        float4 wv = *reinterpret_cast<const float4*>(wr + g * 256);
#pragma unroll
        for (int j = 0; j < 4; ++j) {
          acc[j][g * 4 + 0] += hv[j] * wv.x;
          acc[j][g * 4 + 1] += hv[j] * wv.y;
          acc[j][g * 4 + 2] += hv[j] * wv.z;
          acc[j][g * 4 + 3] += hv[j] * wv.w;
        }
      }
    }
    __syncthreads();
  }

  // ---- epilogue: overwrite routed tokens with mp * expert_out
#pragma unroll
  for (int j = 0; j < 4; ++j) {
    int m = ty * 4 + j;
    if (s_val[m]) {
      float sc = s_mp[m];
      float* ob = out + (size_t)s_tok[m] * DM + tx * 4;
#pragma unroll
      for (int g = 0; g < 4; ++g) {
        float4 r;
        r.x = acc[j][g * 4 + 0] * sc; r.y = acc[j][g * 4 + 1] * sc;
        r.z = acc[j][g * 4 + 2] * sc; r.w = acc[j][g * 4 + 3] * sc;
        *reinterpret_cast<float4*>(ob + g * 256) = r;
      }
    }
  }
}

extern "C" void kernel_launch(void* const* d_in, const int* in_sizes, int n_in,
                              void* d_out, int out_size, void* d_ws, size_t ws_size,
                              hipStream_t stream)
{
  const float* hidden = (const float*)d_in[0];
  const float* rw     = (const float*)d_in[1];
  const float* wi     = (const float*)d_in[2];
  const float* wo     = (const float*)d_in[3];

  float* out        = (float*)d_out;
  float* logits_out = out + (size_t)TOK * DM;          // [B,S,E]
  float* eidx_f     = logits_out + (size_t)TOK * NE;   // [B,S] as float

  uint8_t* ws = (uint8_t*)d_ws;
  int*   eidx   = (int*)ws;                                   // TOK
  float* mp     = (float*)(ws + (size_t)TOK * 4);             // TOK
  int*   slots  = (int*)(ws + (size_t)TOK * 8);               // B*NE*CAP
  int*   counts = (int*)(ws + (size_t)TOK * 8 + (size_t)B_ * NE * CAP * 4); // B*NE

  router_k<<<dim3(TOK / 4), dim3(256), 0, stream>>>(hidden, rw, logits_out, eidx_f, eidx, mp);
  scan_k<<<dim3(B_), dim3(64), 0, stream>>>(eidx, slots, counts);
  passthrough_k<<<dim3((TOK * (DM / 4)) / 256), dim3(256), 0, stream>>>(hidden, mp, out);
  moe_ffn_k<<<dim3(64, NE), dim3(512), 0, stream>>>(hidden, wi, wo, slots, counts, mp, out);
}

// Round 2
// 1336.323 us; speedup vs baseline: 9.8360x; 9.8360x over previous
//
#include <hip/hip_runtime.h>
#include <cstdint>
#include <cstddef>

#define B_  8
#define S_  2048
#define DM  1024
#define FF  4096
#define NE  16
#define CAP 256
#define TOK (B_ * S_)

typedef __attribute__((ext_vector_type(8))) short short8v;
typedef __attribute__((ext_vector_type(4))) float f32x4;
typedef __attribute__((ext_vector_type(4))) unsigned int u32x4;

__device__ __forceinline__ unsigned int bf16r(float x) {
  unsigned int u = __float_as_uint(x);
  return (u + 0x7fffu + ((u >> 16) & 1u)) >> 16;
}
__device__ __forceinline__ unsigned int pkbf(float a, float b) {
  return bf16r(a) | (bf16r(b) << 16);
}

// ---------------- K1: router (one wave per token), fp32 exact ----------------
__global__ __launch_bounds__(256) void router_k(
    const float* __restrict__ hidden, const float* __restrict__ rw,
    float* __restrict__ logits_out, float* __restrict__ eidx_f,
    int* __restrict__ eidx, float* __restrict__ mp)
{
  int wid  = (blockIdx.x * blockDim.x + threadIdx.x) >> 6;
  int lane = threadIdx.x & 63;
  if (wid >= TOK) return;
  const float* h = hidden + (size_t)wid * DM;

  float acc[NE];
#pragma unroll
  for (int e = 0; e < NE; ++e) acc[e] = 0.f;

#pragma unroll
  for (int t = 0; t < 4; ++t) {
    int k0 = t * 256 + lane * 4;
    float4 hv = *reinterpret_cast<const float4*>(h + k0);
    float hx[4] = {hv.x, hv.y, hv.z, hv.w};
#pragma unroll
    for (int j = 0; j < 4; ++j) {
      const float4* r4 = reinterpret_cast<const float4*>(rw + (size_t)(k0 + j) * NE);
      float4 r0 = r4[0], r1 = r4[1], r2 = r4[2], r3 = r4[3];
      acc[0]  += hx[j] * r0.x;  acc[1]  += hx[j] * r0.y;
      acc[2]  += hx[j] * r0.z;  acc[3]  += hx[j] * r0.w;
      acc[4]  += hx[j] * r1.x;  acc[5]  += hx[j] * r1.y;
      acc[6]  += hx[j] * r1.z;  acc[7]  += hx[j] * r1.w;
      acc[8]  += hx[j] * r2.x;  acc[9]  += hx[j] * r2.y;
      acc[10] += hx[j] * r2.z;  acc[11] += hx[j] * r2.w;
      acc[12] += hx[j] * r3.x;  acc[13] += hx[j] * r3.y;
      acc[14] += hx[j] * r3.z;  acc[15] += hx[j] * r3.w;
    }
  }
#pragma unroll
  for (int e = 0; e < NE; ++e) {
    float v = acc[e];
#pragma unroll
    for (int off = 32; off > 0; off >>= 1) v += __shfl_xor(v, off, 64);
    acc[e] = v;
  }
  if (lane < NE) logits_out[(size_t)wid * NE + lane] = acc[lane];
  if (lane == 0) {
    float m = acc[0]; int am = 0;
#pragma unroll
    for (int e = 1; e < NE; ++e) { if (acc[e] > m) { m = acc[e]; am = e; } }
    float s = 0.f;
#pragma unroll
    for (int e = 0; e < NE; ++e) s += expf(acc[e] - m);
    mp[wid]     = 1.f / s;
    eidx[wid]   = am;
    eidx_f[wid] = (float)am;
  }
}

// ---------------- K2: per-batch capacity scan (1 wave per batch) ----------------
__global__ __launch_bounds__(64) void scan_k(
    const int* __restrict__ eidx, int* __restrict__ slots, int* __restrict__ counts)
{
  int b = blockIdx.x;
  int lane = threadIdx.x;
  int cnt[NE];
#pragma unroll
  for (int e = 0; e < NE; ++e) cnt[e] = 0;
  unsigned long long below = (lane == 0) ? 0ull : ((~0ull) >> (64 - lane));

  for (int s0 = 0; s0 < S_; s0 += 64) {
    int e = eidx[b * S_ + s0 + lane];
    int pos = 0;
#pragma unroll
    for (int j = 0; j < NE; ++j) {
      unsigned long long mball = __ballot(e == j);
      if (e == j) pos = cnt[j] + __popcll(mball & below);
      cnt[j] += __popcll(mball);
    }
    if (pos < CAP) slots[((size_t)b * NE + e) * CAP + pos] = s0 + lane;
  }
  if (lane == 0) {
#pragma unroll
    for (int e = 0; e < NE; ++e) counts[b * NE + e] = min(cnt[e], CAP);
  }
}

// ---------------- K3: passthrough: out = mp * hidden (all tokens) ----------------
__global__ __launch_bounds__(256) void passthrough_k(
    const float* __restrict__ hidden, const float* __restrict__ mp, float* __restrict__ out)
{
  size_t i = (size_t)blockIdx.x * blockDim.x + threadIdx.x;
  float4 v = reinterpret_cast<const float4*>(hidden)[i];
  float m = mp[i >> 8];
  float4 r; r.x = v.x * m; r.y = v.y * m; r.z = v.z * m; r.w = v.w * m;
  reinterpret_cast<float4*>(out)[i] = r;
}

// ---------------- build per-expert compacted row list ----------------
__global__ __launch_bounds__(256) void build_rows_k(
    const int* __restrict__ counts, const int* __restrict__ slots,
    int* __restrict__ row2tok, int* __restrict__ rowcnt)
{
  __shared__ int off[B_ + 1];
  const int e = blockIdx.x, t = threadIdx.x;
  if (t == 0) {
    int a = 0;
    for (int b = 0; b < B_; ++b) { off[b] = a; a += counts[b * NE + e]; }
    off[B_] = a; rowcnt[e] = a;
  }
  __syncthreads();
  for (int b = 0; b < B_; ++b) {
    int base = off[b], cnt = off[b + 1] - base;
    for (int i = t; i < cnt; i += 256)
      row2tok[e * 2048 + base + i] = b * S_ + slots[((size_t)b * NE + e) * CAP + i];
  }
}

// ---------------- transpose + fp32->bf16: in[e][M][N] -> out[e][N][M] ----------------
__global__ __launch_bounds__(256) void transpose_cvt_k(
    const float* __restrict__ in, short* __restrict__ outp, int M, int N)
{
  __shared__ float tile[64][65];
  const int nt = blockIdx.x, mt = blockIdx.y, e = blockIdx.z;
  const int t = threadIdx.x;
  const float* src = in + (size_t)e * M * N + (size_t)(mt * 64) * N + nt * 64;
#pragma unroll
  for (int p = 0; p < 4; ++p) {
    int row = p * 16 + (t >> 4);
    int c4  = (t & 15) * 4;
    float4 v = *reinterpret_cast<const float4*>(src + (size_t)row * N + c4);
    tile[row][c4 + 0] = v.x; tile[row][c4 + 1] = v.y;
    tile[row][c4 + 2] = v.z; tile[row][c4 + 3] = v.w;
  }
  __syncthreads();
  short* dst = outp + (size_t)e * N * M + (size_t)(nt * 64) * M + mt * 64;
#pragma unroll
  for (int p = 0; p < 2; ++p) {
    int u = t + p * 256;
    int row = u >> 3, seg = u & 7;
    u32x4 qv;
    qv.x = pkbf(tile[seg * 8 + 0][row], tile[seg * 8 + 1][row]);
    qv.y = pkbf(tile[seg * 8 + 2][row], tile[seg * 8 + 3][row]);
    qv.z = pkbf(tile[seg * 8 + 4][row], tile[seg * 8 + 5][row]);
    qv.w = pkbf(tile[seg * 8 + 6][row], tile[seg * 8 + 7][row]);
    *reinterpret_cast<u32x4*>(dst + (size_t)row * M + seg * 8) = qv;
  }
}

// ---------------- GEMM1: h[e-rows, 4096] = relu(x @ wi), bf16 MFMA 256x256 tiles ----------------
__global__ __launch_bounds__(512, 2) void gemm1_k(
    const float* __restrict__ hidden, const short* __restrict__ wi_t,
    const int* __restrict__ row2tok, const int* __restrict__ rowcnt,
    short* __restrict__ h_ws)
{
  extern __shared__ char smem[];
  short* const bA0 = (short*)smem;
  short* const bA1 = (short*)(smem + 32768);
  short* const bB0 = (short*)(smem + 65536);
  short* const bB1 = (short*)(smem + 98304);
  int* const tok_l = (int*)(smem + 131072);

  const int ft = blockIdx.x, rt = blockIdx.y, e = blockIdx.z;
  const int Re = rowcnt[e];
  if (rt * 256 >= Re) return;
  const int t = threadIdx.x, w = t >> 6, l = t & 63;

  if (t < 256) {
    int r = rt * 256 + t;
    tok_l[t] = row2tok[e * 2048 + (r < Re ? r : 0)];
  }
  __syncthreads();

  const size_t wiB = ((size_t)e * FF + (size_t)ft * 256) * (size_t)DM;

  // prologue: stage kc=0
  {
#pragma unroll
    for (int p = 0; p < 4; ++p) {
      int grp = w * 4 + p;
      int fr = grp * 8 + (l >> 3);
      const short* g = wi_t + wiB + (size_t)fr * DM + (l & 7) * 8;
      __builtin_amdgcn_global_load_lds((const void*)g, (void*)(bB0 + grp * 512), 16, 0, 0);
    }
    float4 sa[8];
#pragma unroll
    for (int p = 0; p < 4; ++p) {
      int u = t + p * 512;
      int row = u >> 3, seg = u & 7;
      const float* g = hidden + (size_t)tok_l[row] * DM + seg * 8;
      sa[p * 2]     = *reinterpret_cast<const float4*>(g);
      sa[p * 2 + 1] = *reinterpret_cast<const float4*>(g + 4);
    }
#pragma unroll
    for (int p = 0; p < 4; ++p) {
      int u = t + p * 512;
      int row = u >> 3, seg = u & 7;
      u32x4 qv;
      qv.x = pkbf(sa[p*2].x, sa[p*2].y);     qv.y = pkbf(sa[p*2].z, sa[p*2].w);
      qv.z = pkbf(sa[p*2+1].x, sa[p*2+1].y); qv.w = pkbf(sa[p*2+1].z, sa[p*2+1].w);
      *reinterpret_cast<u32x4*>(bA0 + row * 64 + seg * 8) = qv;
    }
  }
  __syncthreads();

  f32x4 acc[8][4] = {};
  const int wr = (w >> 2) * 128, wc = (w & 3) * 64;

  for (int ki = 0; ki < 16; ++ki) {
    short* const Ac = (ki & 1) ? bA1 : bA0;
    short* const Bc = (ki & 1) ? bB1 : bB0;
    short* const An = (ki & 1) ? bA0 : bA1;
    short* const Bn = (ki & 1) ? bB0 : bB1;
    const int kn = (ki + 1) * 64;
    float4 sa[8];
    if (ki < 15) {
#pragma unroll
      for (int p = 0; p < 4; ++p) {
        int grp = w * 4 + p;
        int fr = grp * 8 + (l >> 3);
        const short* g = wi_t + wiB + (size_t)fr * DM + kn + (l & 7) * 8;
        __builtin_amdgcn_global_load_lds((const void*)g, (void*)(Bn + grp * 512), 16, 0, 0);
      }
#pragma unroll
      for (int p = 0; p < 4; ++p) {
        int u = t + p * 512;
        int row = u >> 3, seg = u & 7;
        const float* g = hidden + (size_t)tok_l[row] * DM + kn + seg * 8;
        sa[p * 2]     = *reinterpret_cast<const float4*>(g);
        sa[p * 2 + 1] = *reinterpret_cast<const float4*>(g + 4);
      }
    }
#pragma unroll
    for (int ks = 0; ks < 2; ++ks) {
      short8v a[8], b[4];
      const int ko = ks * 32 + (l >> 4) * 8;
      const int lr = l & 15;
#pragma unroll
      for (int i = 0; i < 8; ++i)
        a[i] = *reinterpret_cast<const short8v*>(Ac + (wr + i * 16 + lr) * 64 + ko);
#pragma unroll
      for (int j = 0; j < 4; ++j)
        b[j] = *reinterpret_cast<const short8v*>(Bc + (wc + j * 16 + lr) * 64 + ko);
#pragma unroll
      for (int i = 0; i < 8; ++i)
#pragma unroll
        for (int j = 0; j < 4; ++j)
          acc[i][j] = __builtin_amdgcn_mfma_f32_16x16x32_bf16(a[i], b[j], acc[i][j], 0, 0, 0);
    }
    if (ki < 15) {
#pragma unroll
      for (int p = 0; p < 4; ++p) {
        int u = t + p * 512;
        int row = u >> 3, seg = u & 7;
        u32x4 qv;
        qv.x = pkbf(sa[p*2].x, sa[p*2].y);     qv.y = pkbf(sa[p*2].z, sa[p*2].w);
        qv.z = pkbf(sa[p*2+1].x, sa[p*2+1].y); qv.w = pkbf(sa[p*2+1].z, sa[p*2+1].w);
        *reinterpret_cast<u32x4*>(An + row * 64 + seg * 8) = qv;
      }
    }
    __syncthreads();
  }

  // epilogue: relu + cvt -> LDS repack -> coalesced bf16 store to h_ws
  short* const hre = (short*)smem + w * 8192;
#pragma unroll
  for (int i = 0; i < 8; ++i)
#pragma unroll
    for (int j = 0; j < 4; ++j)
#pragma unroll
      for (int q = 0; q < 4; ++q) {
        int row = i * 16 + (l >> 4) * 4 + q;
        int col = j * 16 + (l & 15);
        hre[row * 64 + col] = (short)bf16r(fmaxf(acc[i][j][q], 0.f));
      }
  __syncthreads();
#pragma unroll
  for (int p = 0; p < 16; ++p) {
    int u = t + p * 512;
    int wreg = u >> 10, unit = u & 1023;
    int row = unit >> 3, seg = unit & 7;
    int grow = rt * 256 + (wreg >> 2) * 128 + row;
    int gcol = ft * 256 + (wreg & 3) * 64 + seg * 8;
    *reinterpret_cast<u32x4*>(h_ws + ((size_t)e * 2048 + grow) * FF + gcol) =
        *reinterpret_cast<const u32x4*>((short*)smem + wreg * 8192 + row * 64 + seg * 8);
  }
}

// ---------------- GEMM2: out_rows = mp * (h @ wo), bf16 MFMA 256x256 tiles ----------------
__global__ __launch_bounds__(512, 2) void gemm2_k(
    const short* __restrict__ h_ws, const short* __restrict__ wo_t,
    const int* __restrict__ row2tok, const int* __restrict__ rowcnt,
    const float* __restrict__ mp, float* __restrict__ out)
{
  extern __shared__ char smem[];
  short* const bA0 = (short*)smem;
  short* const bA1 = (short*)(smem + 32768);
  short* const bB0 = (short*)(smem + 65536);
  short* const bB1 = (short*)(smem + 98304);
  int* const tok_l  = (int*)(smem + 131072);
  float* const mp_l = (float*)(smem + 132096);

  const int dt = blockIdx.x, rt = blockIdx.y, e = blockIdx.z;
  const int Re = rowcnt[e];
  if (rt * 256 >= Re) return;
  const int t = threadIdx.x, w = t >> 6, l = t & 63;

  if (t < 256) {
    int r = rt * 256 + t;
    int tok = row2tok[e * 2048 + (r < Re ? r : 0)];
    tok_l[t] = tok;
    mp_l[t] = mp[tok];
  }
  __syncthreads();

  const size_t hB  = ((size_t)e * 2048 + (size_t)rt * 256) * (size_t)FF;
  const size_t woB = ((size_t)e * DM + (size_t)dt * 256) * (size_t)FF;

  // prologue kc=0
  {
#pragma unroll
    for (int p = 0; p < 4; ++p) {
      int grp = w * 4 + p;
      int rr = grp * 8 + (l >> 3);
      const short* ga = h_ws + hB + (size_t)rr * FF + (l & 7) * 8;
      __builtin_amdgcn_global_load_lds((const void*)ga, (void*)(bA0 + grp * 512), 16, 0, 0);
      const short* gb = wo_t + woB + (size_t)rr * FF + (l & 7) * 8;
      __builtin_amdgcn_global_load_lds((const void*)gb, (void*)(bB0 + grp * 512), 16, 0, 0);
    }
  }
  __syncthreads();

  f32x4 acc[8][4] = {};
  const int wr = (w >> 2) * 128, wc = (w & 3) * 64;

  for (int ki = 0; ki < 64; ++ki) {
    short* const Ac = (ki & 1) ? bA1 : bA0;
    short* const Bc = (ki & 1) ? bB1 : bB0;
    short* const An = (ki & 1) ? bA0 : bA1;
    short* const Bn = (ki & 1) ? bB0 : bB1;
    const int kn = (ki + 1) * 64;
    if (ki < 63) {
#pragma unroll
      for (int p = 0; p < 4; ++p) {
        int grp = w * 4 + p;
        int rr = grp * 8 + (l >> 3);
        const short* ga = h_ws + hB + (size_t)rr * FF + kn + (l & 7) * 8;
        __builtin_amdgcn_global_load_lds((const void*)ga, (void*)(An + grp * 512), 16, 0, 0);
        const short* gb = wo_t + woB + (size_t)rr * FF + kn + (l & 7) * 8;
        __builtin_amdgcn_global_load_lds((const void*)gb, (void*)(Bn + grp * 512), 16, 0, 0);
      }
    }
#pragma unroll
    for (int ks = 0; ks < 2; ++ks) {
      short8v a[8], b[4];
      const int ko = ks * 32 + (l >> 4) * 8;
      const int lr = l & 15;
#pragma unroll
      for (int i = 0; i < 8; ++i)
        a[i] = *reinterpret_cast<const short8v*>(Ac + (wr + i * 16 + lr) * 64 + ko);
#pragma unroll
      for (int j = 0; j < 4; ++j)
        b[j] = *reinterpret_cast<const short8v*>(Bc + (wc + j * 16 + lr) * 64 + ko);
#pragma unroll
      for (int i = 0; i < 8; ++i)
#pragma unroll
        for (int j = 0; j < 4; ++j)
          acc[i][j] = __builtin_amdgcn_mfma_f32_16x16x32_bf16(a[i], b[j], acc[i][j], 0, 0, 0);
    }
    __syncthreads();
  }

  // epilogue: scatter rows, scale by mp
#pragma unroll
  for (int i = 0; i < 8; ++i)
#pragma unroll
    for (int j = 0; j < 4; ++j)
#pragma unroll
      for (int q = 0; q < 4; ++q) {
        int row = wr + i * 16 + (l >> 4) * 4 + q;
        int r = rt * 256 + row;
        if (r < Re) {
          int d = dt * 256 + wc + j * 16 + (l & 15);
          out[(size_t)tok_l[row] * DM + d] = mp_l[row] * acc[i][j][q];
        }
      }
}

// ---------------- fallback: fp32 vector FFN (baseline) ----------------
__global__ __launch_bounds__(512) void moe_ffn_k(
    const float* __restrict__ hidden,
    const float* __restrict__ wi, const float* __restrict__ wo,
    const int* __restrict__ slots, const int* __restrict__ counts,
    const float* __restrict__ mp, float* __restrict__ out)
{
  const int e = blockIdx.y;
  const int tile = blockIdx.x;

  int cnt[B_], off[B_];
  int Rtot = 0;
#pragma unroll
  for (int b = 0; b < B_; ++b) { cnt[b] = counts[b * NE + e]; off[b] = Rtot; Rtot += cnt[b]; }
  const int r0 = tile * 32;
  if (r0 >= Rtot) return;

  __shared__ int   s_tok[32];
  __shared__ float s_mp[32];
  __shared__ int   s_val[32];
  __shared__ float h_lds[32][128];

  const int t = threadIdx.x;
  if (t < 32) {
    int r = r0 + t;
    int tok = 0, val = 0; float m = 0.f;
    if (r < Rtot) {
      int b = 0;
      while (b < B_ - 1 && r >= off[b] + cnt[b]) ++b;
      int c = r - off[b];
      int s = slots[((size_t)b * NE + e) * CAP + c];
      tok = b * S_ + s; val = 1; m = mp[tok];
    }
    s_tok[t] = tok; s_mp[t] = m; s_val[t] = val;
  }
  __syncthreads();

  const int tx = t & 63;
  const int ty = t >> 6;
  const float* wi_e = wi + (size_t)e * DM * FF;
  const float* wo_e = wo + (size_t)e * FF * DM;

  const float* xp[4];
#pragma unroll
  for (int j = 0; j < 4; ++j) xp[j] = hidden + (size_t)s_tok[ty * 4 + j] * DM;

  float acc[4][16];
#pragma unroll
  for (int j = 0; j < 4; ++j)
#pragma unroll
    for (int i = 0; i < 16; ++i) acc[j][i] = 0.f;

  for (int fc = 0; fc < FF; fc += 128) {
    float a1[4][2];
#pragma unroll
    for (int j = 0; j < 4; ++j) { a1[j][0] = 0.f; a1[j][1] = 0.f; }
    const float* wic = wi_e + (size_t)fc + tx;
    for (int k = 0; k < DM; k += 4) {
      float xs[4][4];
#pragma unroll
      for (int j = 0; j < 4; ++j) {
        float4 xv = *reinterpret_cast<const float4*>(xp[j] + k);
        xs[j][0] = xv.x; xs[j][1] = xv.y; xs[j][2] = xv.z; xs[j][3] = xv.w;
      }
      const float* wk = wic + (size_t)k * FF;
#pragma unroll
      for (int q = 0; q < 4; ++q) {
        float wa = wk[(size_t)q * FF];
        float wb = wk[(size_t)q * FF + 64];
#pragma unroll
        for (int j = 0; j < 4; ++j) {
          a1[j][0] += xs[j][q] * wa;
          a1[j][1] += xs[j][q] * wb;
        }
      }
    }
#pragma unroll
    for (int j = 0; j < 4; ++j) {
      h_lds[ty * 4 + j][tx]      = fmaxf(a1[j][0], 0.f);
      h_lds[ty * 4 + j][tx + 64] = fmaxf(a1[j][1], 0.f);
    }
    __syncthreads();

    const float* worow = wo_e + (size_t)fc * DM;
#pragma unroll 2
    for (int f = 0; f < 128; ++f) {
      float hv[4];
#pragma unroll
      for (int j = 0; j < 4; ++j) hv[j] = h_lds[ty * 4 + j][f];
      const float* wrp = worow + (size_t)f * DM + tx * 4;
#pragma unroll
      for (int g = 0; g < 4; ++g) {
        float4 wv = *reinterpret_cast<const float4*>(wrp + g * 256);
#pragma unroll
        for (int j = 0; j < 4; ++j) {
          acc[j][g * 4 + 0] += hv[j] * wv.x;
          acc[j][g * 4 + 1] += hv[j] * wv.y;
          acc[j][g * 4 + 2] += hv[j] * wv.z;
          acc[j][g * 4 + 3] += hv[j] * wv.w;
        }
      }
    }
    __syncthreads();
  }

#pragma unroll
  for (int j = 0; j < 4; ++j) {
    int m = ty * 4 + j;
    if (s_val[m]) {
      float sc = s_mp[m];
      float* ob = out + (size_t)s_tok[m] * DM + tx * 4;
#pragma unroll
      for (int g = 0; g < 4; ++g) {
        float4 r;
        r.x = acc[j][g * 4 + 0] * sc; r.y = acc[j][g * 4 + 1] * sc;
        r.z = acc[j][g * 4 + 2] * sc; r.w = acc[j][g * 4 + 3] * sc;
        *reinterpret_cast<float4*>(ob + g * 256) = r;
      }
    }
  }
}

extern "C" void kernel_launch(void* const* d_in, const int* in_sizes, int n_in,
                              void* d_out, int out_size, void* d_ws, size_t ws_size,
                              hipStream_t stream)
{
  const float* hidden = (const float*)d_in[0];
  const float* rw     = (const float*)d_in[1];
  const float* wi     = (const float*)d_in[2];
  const float* wo     = (const float*)d_in[3];

  float* out        = (float*)d_out;
  float* logits_out = out + (size_t)TOK * DM;
  float* eidx_f     = logits_out + (size_t)TOK * NE;

  uint8_t* ws = (uint8_t*)d_ws;
  const size_t NEED = 537265216ull;

  if (ws_size >= NEED) {
    short* wi_t  = (short*)(ws);
    short* wo_t  = (short*)(ws + 134217728ull);
    short* h_ws  = (short*)(ws + 268435456ull);
    int*   eidx  = (int*)(ws + 536870912ull);
    float* mpv   = (float*)(ws + 536936448ull);
    int*   slots = (int*)(ws + 537001984ull);
    int*   cnts  = (int*)(ws + 537133056ull);
    int*   r2t   = (int*)(ws + 537134080ull);
    int*   rcnt  = (int*)(ws + 537265152ull);

    hipFuncSetAttribute((const void*)gemm1_k, hipFuncAttributeMaxDynamicSharedMemorySize, 132096);
    hipFuncSetAttribute((const void*)gemm2_k, hipFuncAttributeMaxDynamicSharedMemorySize, 133120);

    router_k<<<dim3(TOK / 4), 256, 0, stream>>>(hidden, rw, logits_out, eidx_f, eidx, mpv);
    scan_k<<<dim3(B_), 64, 0, stream>>>(eidx, slots, cnts);
    build_rows_k<<<dim3(NE), 256, 0, stream>>>(cnts, slots, r2t, rcnt);
    transpose_cvt_k<<<dim3(FF / 64, DM / 64, NE), 256, 0, stream>>>(wi, wi_t, DM, FF);
    transpose_cvt_k<<<dim3(DM / 64, FF / 64, NE), 256, 0, stream>>>(wo, wo_t, FF, DM);
    passthrough_k<<<dim3((TOK * (DM / 4)) / 256), 256, 0, stream>>>(hidden, mpv, out);
    gemm1_k<<<dim3(16, 8, NE), 512, 132096, stream>>>(hidden, wi_t, r2t, rcnt, h_ws);
    gemm2_k<<<dim3(4, 8, NE), 512, 133120, stream>>>(h_ws, wo_t, r2t, rcnt, mpv, out);
  } else {
    int*   eidx   = (int*)ws;
    float* mpv    = (float*)(ws + (size_t)TOK * 4);
    int*   slots  = (int*)(ws + (size_t)TOK * 8);
    int*   cnts   = (int*)(ws + (size_t)TOK * 8 + (size_t)B_ * NE * CAP * 4);

    router_k<<<dim3(TOK / 4), 256, 0, stream>>>(hidden, rw, logits_out, eidx_f, eidx, mpv);
    scan_k<<<dim3(B_), 64, 0, stream>>>(eidx, slots, cnts);
    passthrough_k<<<dim3((TOK * (DM / 4)) / 256), 256, 0, stream>>>(hidden, mpv, out);
    moe_ffn_k<<<dim3(64, NE), 512, 0, stream>>>(hidden, wi, wo, slots, cnts, mpv, out);
  }
}